// Round 1
// baseline (3484.278 us; speedup 1.0000x reference)
//
#include <hip/hip_runtime.h>

#define D 128
#define BN_EPS 1e-5f

// deg[i] = 1 (self loop)
__global__ __launch_bounds__(256) void k_init_deg(float* __restrict__ deg, int n) {
    int i = blockIdx.x * 256 + threadIdx.x;
    if (i < n) deg[i] = 1.0f;
}

// deg[dst[e]] += 1 per real edge
__global__ __launch_bounds__(256) void k_deg_edges(const int* __restrict__ dst,
                                                   float* __restrict__ deg, int E) {
    int e = blockIdx.x * 256 + threadIdx.x;
    if (e < E) atomicAdd(&deg[dst[e]], 1.0f);
}

// deg -> rsqrt(deg)  (deg >= 1 always, self loops)
__global__ __launch_bounds__(256) void k_dinv(float* __restrict__ deg, int n) {
    int i = blockIdx.x * 256 + threadIdx.x;
    if (i < n) deg[i] = rsqrtf(deg[i]);
}

// Y[n,128] = X[n,128] @ W[128,128].  W staged in LDS (64 KB), 64 rows/block.
__global__ __launch_bounds__(256) void k_gemm(const float* __restrict__ X,
                                              const float* __restrict__ W,
                                              float* __restrict__ Y, int n) {
    __shared__ float Ws[D * D];
    {
        const float4* W4 = (const float4*)W;
        float4* Ws4 = (float4*)Ws;
        for (int i = threadIdx.x; i < D * D / 4; i += 256) Ws4[i] = W4[i];
    }
    __syncthreads();
    int j = threadIdx.x & (D - 1);   // output column
    int sub = threadIdx.x >> 7;      // 0/1 — interleaved rows
    int row0 = blockIdx.x * 64;
    int rend = min(row0 + 64, n);
    for (int r = row0 + sub; r < rend; r += 2) {
        const float4* x4 = (const float4*)(X + (size_t)r * D);
        float acc = 0.f;
#pragma unroll
        for (int k4 = 0; k4 < D / 4; k4++) {
            float4 xv = x4[k4];
            acc = fmaf(xv.x, Ws[(k4 * 4 + 0) * D + j], acc);
            acc = fmaf(xv.y, Ws[(k4 * 4 + 1) * D + j], acc);
            acc = fmaf(xv.z, Ws[(k4 * 4 + 2) * D + j], acc);
            acc = fmaf(xv.w, Ws[(k4 * 4 + 3) * D + j], acc);
        }
        Y[(size_t)r * D + j] = acc;
    }
}

// One 32-lane group per (edge or self-loop): OUT[dst] += dinv[s]*dinv[t] * H[src]
__global__ __launch_bounds__(256) void k_aggregate(const float* __restrict__ H,
                                                   const int* __restrict__ src,
                                                   const int* __restrict__ dst,
                                                   const float* __restrict__ dinv,
                                                   float* __restrict__ OUT,
                                                   int E, int n) {
    int g = blockIdx.x * 8 + (threadIdx.x >> 5);
    int lane = threadIdx.x & 31;
    if (g >= E + n) return;
    int s, t;
    float w;
    if (g < E) {
        s = src[g];
        t = dst[g];
        w = dinv[s] * dinv[t];
    } else {
        s = g - E;
        t = s;
        float di = dinv[s];
        w = di * di;
    }
    float4 v = ((const float4*)(H + (size_t)s * D))[lane];
    float* o = OUT + (size_t)t * D + lane * 4;
    atomicAdd(o + 0, w * v.x);
    atomicAdd(o + 1, w * v.y);
    atomicAdd(o + 2, w * v.z);
    atomicAdd(o + 3, w * v.w);
}

// per-column sum / sumsq partials -> atomic combine. sums[0:128]=sum, sums[128:256]=sumsq
__global__ __launch_bounds__(128) void k_bn_stats(const float* __restrict__ A,
                                                  float* __restrict__ sums, int n) {
    int j = threadIdx.x;
    float s = 0.f, ss = 0.f;
    for (int r = blockIdx.x; r < n; r += gridDim.x) {
        float v = A[(size_t)r * D + j];
        s += v;
        ss += v * v;
    }
    atomicAdd(&sums[j], s);
    atomicAdd(&sums[D + j], ss);
}

// sc[0:128]=scale, sc[128:256]=shift.  (b1 cancels exactly in BN — omitted.)
__global__ __launch_bounds__(128) void k_bn_finalize(const float* __restrict__ sums,
                                                     const float* __restrict__ gamma,
                                                     const float* __restrict__ beta,
                                                     float* __restrict__ sc, int n) {
    int j = threadIdx.x;
    float inv_n = 1.0f / (float)n;
    float mu = sums[j] * inv_n;
    float var = sums[D + j] * inv_n - mu * mu;
    float is = rsqrtf(var + BN_EPS);
    float scale = gamma[j] * is;
    sc[j] = scale;
    sc[D + j] = beta[j] - mu * scale;
}

// A = relu(A*scale + shift), in place, float4
__global__ __launch_bounds__(256) void k_bn_apply_relu(float* __restrict__ A,
                                                       const float* __restrict__ sc,
                                                       int total4) {
    int i = blockIdx.x * 256 + threadIdx.x;
    if (i >= total4) return;
    int c4 = i & (D / 4 - 1);
    float4 v = ((float4*)A)[i];
    float4 s = ((const float4*)sc)[c4];
    float4 b = ((const float4*)(sc + D))[c4];
    v.x = fmaxf(fmaf(v.x, s.x, b.x), 0.f);
    v.y = fmaxf(fmaf(v.y, s.y, b.y), 0.f);
    v.z = fmaxf(fmaf(v.z, s.z, b.z), 0.f);
    v.w = fmaxf(fmaf(v.w, s.w, b.w), 0.f);
    ((float4*)A)[i] = v;
}

// OUT[i,:] = b2  (bias added after aggregation; atomics accumulate on top)
__global__ __launch_bounds__(256) void k_init_out(float* __restrict__ OUT,
                                                  const float* __restrict__ b,
                                                  int total4) {
    int i = blockIdx.x * 256 + threadIdx.x;
    if (i >= total4) return;
    ((float4*)OUT)[i] = ((const float4*)b)[i & (D / 4 - 1)];
}

extern "C" void kernel_launch(void* const* d_in, const int* in_sizes, int n_in,
                              void* d_out, int out_size, void* d_ws, size_t ws_size,
                              hipStream_t stream) {
    const float* x     = (const float*)d_in[0];
    const int*   ei    = (const int*)d_in[1];
    const float* W1    = (const float*)d_in[2];
    // d_in[3] = b1 — cancels exactly in BatchNorm, unused
    const float* gamma = (const float*)d_in[4];
    const float* beta  = (const float*)d_in[5];
    const float* W2    = (const float*)d_in[6];
    const float* b2    = (const float*)d_in[7];
    float* out = (float*)d_out;

    int n = in_sizes[0] / D;       // 50000
    int E = in_sizes[1] / 2;       // 800000
    const int* src = ei;
    const int* dst = ei + E;

    char* ws = (char*)d_ws;
    size_t szH = (size_t)n * D * sizeof(float);
    float* h    = (float*)(ws);                 // x@W1, later h2@W2
    float* agg  = (float*)(ws + szH);           // conv1 aggregation / BN in-place
    float* dinv = (float*)(ws + 2 * szH);       // deg -> rsqrt(deg)
    size_t offSums = 2 * szH + (((size_t)n * sizeof(float) + 511) & ~(size_t)511);
    float* sums = (float*)(ws + offSums);       // 256 floats: colsum, colsumsq
    float* sc   = sums + 2 * D;                 // 256 floats: scale, shift

    int total4 = n * D / 4;
    int groups = E + n;

    hipMemsetAsync(agg, 0, szH, stream);
    hipMemsetAsync(sums, 0, 2 * D * sizeof(float), stream);

    k_init_deg<<<(n + 255) / 256, 256, 0, stream>>>(dinv, n);
    k_deg_edges<<<(E + 255) / 256, 256, 0, stream>>>(dst, dinv, E);
    k_dinv<<<(n + 255) / 256, 256, 0, stream>>>(dinv, n);

    k_gemm<<<(n + 63) / 64, 256, 0, stream>>>(x, W1, h, n);
    k_aggregate<<<(groups + 7) / 8, 256, 0, stream>>>(h, src, dst, dinv, agg, E, n);

    k_bn_stats<<<512, 128, 0, stream>>>(agg, sums, n);
    k_bn_finalize<<<1, 128, 0, stream>>>(sums, gamma, beta, sc, n);
    k_bn_apply_relu<<<(total4 + 255) / 256, 256, 0, stream>>>(agg, sc, total4);

    k_gemm<<<(n + 63) / 64, 256, 0, stream>>>(agg, W2, h, n);
    k_init_out<<<(total4 + 255) / 256, 256, 0, stream>>>(out, b2, total4);
    k_aggregate<<<(groups + 7) / 8, 256, 0, stream>>>(h, src, dst, dinv, out, E, n);
}

// Round 2
// 552.633 us; speedup vs baseline: 6.3049x; 6.3049x over previous
//
#include <hip/hip_runtime.h>

#define D 128
#define BN_EPS 1e-5f

// ---------------- degree / dinv ----------------
__global__ __launch_bounds__(256) void k_count(const int* __restrict__ dst,
                                               int* __restrict__ cnt, int E) {
    int e = blockIdx.x * 256 + threadIdx.x;
    if (e < E) atomicAdd(&cnt[dst[e]], 1);
}

// dinv[i] = rsqrt(cnt[i] + 1)   (+1 = self loop)
__global__ __launch_bounds__(256) void k_dinv(const int* __restrict__ cnt,
                                              float* __restrict__ dinv, int n) {
    int i = blockIdx.x * 256 + threadIdx.x;
    if (i < n) dinv[i] = rsqrtf((float)(cnt[i] + 1));
}

// ---------------- exclusive scan (single block, 1024 threads) ----------------
__global__ __launch_bounds__(1024) void k_scan(const int* __restrict__ cnt,
                                               int* __restrict__ rowptr,
                                               int* __restrict__ cursor, int n) {
    __shared__ int part[1024];
    int tid = threadIdx.x;
    int chunk = (n + 1023) / 1024;
    int s0 = tid * chunk, s1 = min(s0 + chunk, n);
    int s = 0;
    for (int i = s0; i < s1; i++) s += cnt[i];
    part[tid] = s;
    __syncthreads();
    for (int off = 1; off < 1024; off <<= 1) {
        int v = (tid >= off) ? part[tid - off] : 0;
        __syncthreads();
        part[tid] += v;
        __syncthreads();
    }
    int base = (tid == 0) ? 0 : part[tid - 1];
    for (int i = s0; i < s1; i++) {
        rowptr[i] = base;
        cursor[i] = base;
        base += cnt[i];
    }
    if (tid == 1023) rowptr[n] = part[1023];
}

// ---------------- scatter edges into CSR slots ----------------
__global__ __launch_bounds__(256) void k_scatter(const int* __restrict__ src,
                                                 const int* __restrict__ dst,
                                                 const float* __restrict__ dinv,
                                                 int* __restrict__ cursor,
                                                 int* __restrict__ csr_src,
                                                 float* __restrict__ csr_w, int E) {
    int e = blockIdx.x * 256 + threadIdx.x;
    if (e >= E) return;
    int s = src[e], t = dst[e];
    int pos = atomicAdd(&cursor[t], 1);
    csr_src[pos] = s;
    csr_w[pos] = dinv[s];   // pre-fold source normalization
}

// ---------------- gather aggregation: one wave per output row ----------------
// OUT[t] = dinv[t] * ( sum_{s in N(t)} dinv[s]*H[s] + dinv[t]*H[t] ) + bias
__global__ __launch_bounds__(256) void k_agg_rows(const float* __restrict__ H,
                                                  const int* __restrict__ rowptr,
                                                  const int* __restrict__ csr_src,
                                                  const float* __restrict__ csr_w,
                                                  const float* __restrict__ dinv,
                                                  const float* __restrict__ bias,
                                                  float* __restrict__ OUT, int n) {
    int row = blockIdx.x * 4 + (threadIdx.x >> 6);
    if (row >= n) return;
    int lane = threadIdx.x & 63;
    const float2* H2 = (const float2*)H;
    float dt = dinv[row];
    float2 hv = H2[(size_t)row * 64 + lane];
    float ax = dt * hv.x, ay = dt * hv.y;            // self loop, weight dinv[t]
    int k0 = rowptr[row], k1 = rowptr[row + 1];
    for (int k = k0; k < k1; k++) {
        int s = csr_src[k];
        float w = csr_w[k];
        float2 v = H2[(size_t)s * 64 + lane];
        ax = fmaf(w, v.x, ax);
        ay = fmaf(w, v.y, ay);
    }
    ax *= dt;
    ay *= dt;
    if (bias) {
        ax += bias[lane * 2];
        ay += bias[lane * 2 + 1];
    }
    ((float2*)OUT)[(size_t)row * 64 + lane] = make_float2(ax, ay);
}

// ---------------- tiled GEMM: Y[n,128] = f(X)[n,128] @ W[128,128] ----------------
// f = identity if sc==null, else relu(x*scale + shift) with sc[0:128]=scale, sc[128:256]=shift
#define XS_STRIDE 68   // 64 rows + pad (float4-aligned, breaks bank aliasing)
__global__ __launch_bounds__(256) void k_gemm(const float* __restrict__ X,
                                              const float* __restrict__ W,
                                              const float* __restrict__ sc,
                                              float* __restrict__ Y, int n) {
    __shared__ float XsT[32 * XS_STRIDE];   // [kk][row], transposed chunk
    __shared__ float Ws[32 * 132];          // [kk][c], padded stride
    int tid = threadIdx.x;
    int row0 = blockIdx.x * 64;
    int rg = tid & 15;   // rows rg*4 .. rg*4+3
    int cg = tid >> 4;   // cols cg*8 .. cg*8+7
    float acc[4][8];
#pragma unroll
    for (int i = 0; i < 4; i++)
#pragma unroll
        for (int j = 0; j < 8; j++) acc[i][j] = 0.f;

    for (int kc = 0; kc < 4; kc++) {
        __syncthreads();
        // stage W chunk (32 k x 128 c)
        {
            int idx = tid;
#pragma unroll
            for (int p = 0; p < 4; p++, idx += 256) {
                int k = idx >> 5, c4 = idx & 31;
                float4 w = ((const float4*)(W + (size_t)(kc * 32 + k) * D))[c4];
                float* dpt = &Ws[k * 132 + c4 * 4];
                dpt[0] = w.x; dpt[1] = w.y; dpt[2] = w.z; dpt[3] = w.w;
            }
        }
        // stage X chunk transposed (64 rows x 32 k), optional BN+ReLU on load
        {
            int r = tid >> 3, kq = tid & 7;
#pragma unroll
            for (int p = 0; p < 2; p++, r += 32) {
                int grow = row0 + r;
                float4 v = make_float4(0.f, 0.f, 0.f, 0.f);
                if (grow < n)
                    v = *(const float4*)(X + (size_t)grow * D + kc * 32 + kq * 4);
                if (sc) {
                    int c4 = kc * 8 + kq;
                    float4 scl = ((const float4*)sc)[c4];
                    float4 sh  = ((const float4*)(sc + D))[c4];
                    v.x = fmaxf(fmaf(v.x, scl.x, sh.x), 0.f);
                    v.y = fmaxf(fmaf(v.y, scl.y, sh.y), 0.f);
                    v.z = fmaxf(fmaf(v.z, scl.z, sh.z), 0.f);
                    v.w = fmaxf(fmaf(v.w, scl.w, sh.w), 0.f);
                }
                XsT[(kq * 4 + 0) * XS_STRIDE + r] = v.x;
                XsT[(kq * 4 + 1) * XS_STRIDE + r] = v.y;
                XsT[(kq * 4 + 2) * XS_STRIDE + r] = v.z;
                XsT[(kq * 4 + 3) * XS_STRIDE + r] = v.w;
            }
        }
        __syncthreads();
#pragma unroll 4
        for (int kk = 0; kk < 32; kk++) {
            float4 xv = *(const float4*)&XsT[kk * XS_STRIDE + rg * 4];
            float4 wa = *(const float4*)&Ws[kk * 132 + cg * 8];
            float4 wb = *(const float4*)&Ws[kk * 132 + cg * 8 + 4];
            float xr[4] = {xv.x, xv.y, xv.z, xv.w};
            float wc[8] = {wa.x, wa.y, wa.z, wa.w, wb.x, wb.y, wb.z, wb.w};
#pragma unroll
            for (int i = 0; i < 4; i++)
#pragma unroll
                for (int j = 0; j < 8; j++)
                    acc[i][j] = fmaf(xr[i], wc[j], acc[i][j]);
        }
    }
#pragma unroll
    for (int i = 0; i < 4; i++) {
        int grow = row0 + rg * 4 + i;
        if (grow < n) {
            *(float4*)(Y + (size_t)grow * D + cg * 8) =
                make_float4(acc[i][0], acc[i][1], acc[i][2], acc[i][3]);
            *(float4*)(Y + (size_t)grow * D + cg * 8 + 4) =
                make_float4(acc[i][4], acc[i][5], acc[i][6], acc[i][7]);
        }
    }
}

// ---------------- BN stats ----------------
__global__ __launch_bounds__(128) void k_bn_stats(const float* __restrict__ A,
                                                  float* __restrict__ sums, int n) {
    int j = threadIdx.x;
    float s = 0.f, ss = 0.f;
    for (int r = blockIdx.x; r < n; r += gridDim.x) {
        float v = A[(size_t)r * D + j];
        s += v;
        ss += v * v;
    }
    atomicAdd(&sums[j], s);
    atomicAdd(&sums[D + j], ss);
}

// sc[0:128]=scale, sc[128:256]=shift.  (b1 cancels exactly in BN — omitted.)
__global__ __launch_bounds__(128) void k_bn_finalize(const float* __restrict__ sums,
                                                     const float* __restrict__ gamma,
                                                     const float* __restrict__ beta,
                                                     float* __restrict__ sc, int n) {
    int j = threadIdx.x;
    float inv_n = 1.0f / (float)n;
    float mu = sums[j] * inv_n;
    float var = sums[D + j] * inv_n - mu * mu;
    float is = rsqrtf(var + BN_EPS);
    float scale = gamma[j] * is;
    sc[j] = scale;
    sc[D + j] = beta[j] - mu * scale;
}

extern "C" void kernel_launch(void* const* d_in, const int* in_sizes, int n_in,
                              void* d_out, int out_size, void* d_ws, size_t ws_size,
                              hipStream_t stream) {
    const float* x     = (const float*)d_in[0];
    const int*   ei    = (const int*)d_in[1];
    const float* W1    = (const float*)d_in[2];
    // d_in[3] = b1 — cancels exactly in BatchNorm, unused
    const float* gamma = (const float*)d_in[4];
    const float* beta  = (const float*)d_in[5];
    const float* W2    = (const float*)d_in[6];
    const float* b2    = (const float*)d_in[7];
    float* out = (float*)d_out;

    int n = in_sizes[0] / D;   // 50000
    int E = in_sizes[1] / 2;   // 800000
    const int* src = ei;
    const int* dst = ei + E;

    char* ws = (char*)d_ws;
    size_t off = 0;
    auto alloc = [&](size_t bytes) {
        char* p = ws + off;
        off = (off + bytes + 511) & ~(size_t)511;
        return p;
    };
    size_t szH = (size_t)n * D * sizeof(float);
    float* h       = (float*)alloc(szH);
    float* agg     = (float*)alloc(szH);
    float* dinv    = (float*)alloc(n * sizeof(float));
    int*   cnt     = (int*)alloc(n * sizeof(int));
    int*   rowptr  = (int*)alloc((n + 1) * sizeof(int));
    int*   cursor  = (int*)alloc(n * sizeof(int));
    int*   csr_src = (int*)alloc((size_t)E * sizeof(int));
    float* csr_w   = (float*)alloc((size_t)E * sizeof(float));
    float* sums    = (float*)alloc(2 * D * sizeof(float));
    float* sc      = (float*)alloc(2 * D * sizeof(float));

    hipMemsetAsync(cnt, 0, n * sizeof(int), stream);
    hipMemsetAsync(sums, 0, 2 * D * sizeof(float), stream);

    // CSR build
    k_count<<<(E + 255) / 256, 256, 0, stream>>>(dst, cnt, E);
    k_dinv<<<(n + 255) / 256, 256, 0, stream>>>(cnt, dinv, n);
    k_scan<<<1, 1024, 0, stream>>>(cnt, rowptr, cursor, n);
    k_scatter<<<(E + 255) / 256, 256, 0, stream>>>(src, dst, dinv, cursor,
                                                   csr_src, csr_w, E);

    // conv1: h = x @ W1 ; agg = norm-aggregate(h)   (b1 cancels in BN)
    k_gemm<<<(n + 63) / 64, 256, 0, stream>>>(x, W1, nullptr, h, n);
    k_agg_rows<<<(n + 3) / 4, 256, 0, stream>>>(h, rowptr, csr_src, csr_w, dinv,
                                                nullptr, agg, n);

    // BN stats -> scale/shift (ReLU fused into GEMM2 load)
    k_bn_stats<<<512, 128, 0, stream>>>(agg, sums, n);
    k_bn_finalize<<<1, 128, 0, stream>>>(sums, gamma, beta, sc, n);

    // conv2: h = relu(BN(agg)) @ W2 ; out = norm-aggregate(h) + b2
    k_gemm<<<(n + 63) / 64, 256, 0, stream>>>(agg, W2, sc, h, n);
    k_agg_rows<<<(n + 3) / 4, 256, 0, stream>>>(h, rowptr, csr_src, csr_w, dinv,
                                                b2, out, n);
}

// Round 3
// 397.630 us; speedup vs baseline: 8.7626x; 1.3898x over previous
//
#include <hip/hip_runtime.h>

#define D 128
#define BN_EPS 1e-5f

// ---------------- degree count ----------------
__global__ __launch_bounds__(256) void k_count(const int* __restrict__ dst,
                                               int* __restrict__ cnt, int E) {
    int e = blockIdx.x * 256 + threadIdx.x;
    if (e < E) atomicAdd(&cnt[dst[e]], 1);
}

// ---------------- 3-phase exclusive scan over cnt[0:n] ----------------
// Phase A: per-block (1024 elems) reduction -> bsum[b]
__global__ __launch_bounds__(256) void k_scanA(const int* __restrict__ cnt,
                                               int* __restrict__ bsum, int n) {
    int tid = threadIdx.x;
    int base = blockIdx.x * 1024 + tid * 4;
    int s = 0;
#pragma unroll
    for (int i = 0; i < 4; i++) {
        int idx = base + i;
        if (idx < n) s += cnt[idx];
    }
#pragma unroll
    for (int off = 32; off; off >>= 1) s += __shfl_down(s, off, 64);
    __shared__ int ws[4];
    if ((tid & 63) == 0) ws[tid >> 6] = s;
    __syncthreads();
    if (tid == 0) bsum[blockIdx.x] = ws[0] + ws[1] + ws[2] + ws[3];
}

// Phase B: single small block scans block sums (nb <= 256); writes rowptr[n]=total
__global__ __launch_bounds__(256) void k_scanB(int* __restrict__ bsum,
                                               int* __restrict__ rowptr,
                                               int nb, int n) {
    __shared__ int sh[256];
    int tid = threadIdx.x;
    int v = (tid < nb) ? bsum[tid] : 0;
    sh[tid] = v;
    __syncthreads();
    for (int off = 1; off < 256; off <<= 1) {
        int u = (tid >= off) ? sh[tid - off] : 0;
        __syncthreads();
        sh[tid] += u;
        __syncthreads();
    }
    if (tid < nb) bsum[tid] = sh[tid] - v;   // exclusive
    if (tid == nb - 1) rowptr[n] = sh[tid];  // total
}

// Phase C: block-local exclusive scan + block offset; also writes cursor & dinv
__global__ __launch_bounds__(256) void k_scanC(const int* __restrict__ cnt,
                                               const int* __restrict__ bsum,
                                               int* __restrict__ rowptr,
                                               int* __restrict__ cursor,
                                               float* __restrict__ dinv, int n) {
    int tid = threadIdx.x;
    int base = blockIdx.x * 1024 + tid * 4;
    int c[4];
    int s = 0;
#pragma unroll
    for (int i = 0; i < 4; i++) {
        int idx = base + i;
        c[i] = (idx < n) ? cnt[idx] : 0;
        s += c[i];
    }
    int inc = s;
#pragma unroll
    for (int off = 1; off < 64; off <<= 1) {
        int u = __shfl_up(inc, off, 64);
        if ((tid & 63) >= off) inc += u;
    }
    __shared__ int wtot[4];
    if ((tid & 63) == 63) wtot[tid >> 6] = inc;
    __syncthreads();
    int woff = 0, w = tid >> 6;
    for (int i = 0; i < w; i++) woff += wtot[i];
    int ex = inc - s + woff + bsum[blockIdx.x];
#pragma unroll
    for (int i = 0; i < 4; i++) {
        int idx = base + i;
        if (idx < n) {
            rowptr[idx] = ex;
            cursor[idx] = ex;
            dinv[idx] = rsqrtf((float)(c[i] + 1));  // +1 = self loop
            ex += c[i];
        }
    }
}

// ---------------- scatter edges into CSR slots ----------------
__global__ __launch_bounds__(256) void k_scatter(const int* __restrict__ src,
                                                 const int* __restrict__ dst,
                                                 const float* __restrict__ dinv,
                                                 int* __restrict__ cursor,
                                                 int* __restrict__ csr_src,
                                                 float* __restrict__ csr_w, int E) {
    int e = blockIdx.x * 256 + threadIdx.x;
    if (e >= E) return;
    int s = src[e], t = dst[e];
    int pos = atomicAdd(&cursor[t], 1);
    csr_src[pos] = s;
    csr_w[pos] = dinv[s];   // pre-fold source normalization
}

// ---------------- gather aggregation: one wave per output row ----------------
// OUT[t] = dinv[t] * ( sum_{s in N(t)} dinv[s]*H[s] + dinv[t]*H[t] ) + bias
__global__ __launch_bounds__(256) void k_agg_rows(const float* __restrict__ H,
                                                  const int* __restrict__ rowptr,
                                                  const int* __restrict__ csr_src,
                                                  const float* __restrict__ csr_w,
                                                  const float* __restrict__ dinv,
                                                  const float* __restrict__ bias,
                                                  float* __restrict__ OUT, int n) {
    int row = blockIdx.x * 4 + (threadIdx.x >> 6);
    if (row >= n) return;
    int lane = threadIdx.x & 63;
    const float2* H2 = (const float2*)H;
    float dt = dinv[row];
    float2 hv = H2[(size_t)row * 64 + lane];
    float ax = dt * hv.x, ay = dt * hv.y;            // self loop, weight dinv[t]
    int k0 = rowptr[row], k1 = rowptr[row + 1];
    int k = k0;
    for (; k + 1 < k1; k += 2) {
        int s0 = csr_src[k], s1 = csr_src[k + 1];
        float w0 = csr_w[k], w1 = csr_w[k + 1];
        float2 v0 = H2[(size_t)s0 * 64 + lane];
        float2 v1 = H2[(size_t)s1 * 64 + lane];
        ax = fmaf(w0, v0.x, ax);
        ay = fmaf(w0, v0.y, ay);
        ax = fmaf(w1, v1.x, ax);
        ay = fmaf(w1, v1.y, ay);
    }
    if (k < k1) {
        int s = csr_src[k];
        float w = csr_w[k];
        float2 v = H2[(size_t)s * 64 + lane];
        ax = fmaf(w, v.x, ax);
        ay = fmaf(w, v.y, ay);
    }
    ax *= dt;
    ay *= dt;
    if (bias) {
        ax += bias[lane * 2];
        ay += bias[lane * 2 + 1];
    }
    ((float2*)OUT)[(size_t)row * 64 + lane] = make_float2(ax, ay);
}

// ---------------- tiled GEMM: Y[n,128] = f(X)[n,128] @ W[128,128] ----------------
// f = identity if sc==null, else relu(x*scale + shift) with sc[0:128]=scale, sc[128:256]=shift
#define XS_STRIDE 68   // 64 rows + pad (float4-aligned, breaks bank aliasing)
__global__ __launch_bounds__(256) void k_gemm(const float* __restrict__ X,
                                              const float* __restrict__ W,
                                              const float* __restrict__ sc,
                                              float* __restrict__ Y, int n) {
    __shared__ float XsT[32 * XS_STRIDE];   // [kk][row], transposed chunk
    __shared__ float Ws[32 * 132];          // [kk][c], padded stride
    int tid = threadIdx.x;
    int row0 = blockIdx.x * 64;
    int rg = tid & 15;   // rows rg*4 .. rg*4+3
    int cg = tid >> 4;   // cols cg*8 .. cg*8+7
    float acc[4][8];
#pragma unroll
    for (int i = 0; i < 4; i++)
#pragma unroll
        for (int j = 0; j < 8; j++) acc[i][j] = 0.f;

    for (int kc = 0; kc < 4; kc++) {
        __syncthreads();
        // stage W chunk (32 k x 128 c)
        {
            int idx = tid;
#pragma unroll
            for (int p = 0; p < 4; p++, idx += 256) {
                int k = idx >> 5, c4 = idx & 31;
                float4 w = ((const float4*)(W + (size_t)(kc * 32 + k) * D))[c4];
                float* dpt = &Ws[k * 132 + c4 * 4];
                dpt[0] = w.x; dpt[1] = w.y; dpt[2] = w.z; dpt[3] = w.w;
            }
        }
        // stage X chunk transposed (64 rows x 32 k), optional BN+ReLU on load
        {
            int r = tid >> 3, kq = tid & 7;
#pragma unroll
            for (int p = 0; p < 2; p++, r += 32) {
                int grow = row0 + r;
                float4 v = make_float4(0.f, 0.f, 0.f, 0.f);
                if (grow < n)
                    v = *(const float4*)(X + (size_t)grow * D + kc * 32 + kq * 4);
                if (sc) {
                    int c4 = kc * 8 + kq;
                    float4 scl = ((const float4*)sc)[c4];
                    float4 sh  = ((const float4*)(sc + D))[c4];
                    v.x = fmaxf(fmaf(v.x, scl.x, sh.x), 0.f);
                    v.y = fmaxf(fmaf(v.y, scl.y, sh.y), 0.f);
                    v.z = fmaxf(fmaf(v.z, scl.z, sh.z), 0.f);
                    v.w = fmaxf(fmaf(v.w, scl.w, sh.w), 0.f);
                }
                XsT[(kq * 4 + 0) * XS_STRIDE + r] = v.x;
                XsT[(kq * 4 + 1) * XS_STRIDE + r] = v.y;
                XsT[(kq * 4 + 2) * XS_STRIDE + r] = v.z;
                XsT[(kq * 4 + 3) * XS_STRIDE + r] = v.w;
            }
        }
        __syncthreads();
#pragma unroll 4
        for (int kk = 0; kk < 32; kk++) {
            float4 xv = *(const float4*)&XsT[kk * XS_STRIDE + rg * 4];
            float4 wa = *(const float4*)&Ws[kk * 132 + cg * 8];
            float4 wb = *(const float4*)&Ws[kk * 132 + cg * 8 + 4];
            float xr[4] = {xv.x, xv.y, xv.z, xv.w};
            float wc[8] = {wa.x, wa.y, wa.z, wa.w, wb.x, wb.y, wb.z, wb.w};
#pragma unroll
            for (int i = 0; i < 4; i++)
#pragma unroll
                for (int j = 0; j < 8; j++)
                    acc[i][j] = fmaf(xr[i], wc[j], acc[i][j]);
        }
    }
#pragma unroll
    for (int i = 0; i < 4; i++) {
        int grow = row0 + rg * 4 + i;
        if (grow < n) {
            *(float4*)(Y + (size_t)grow * D + cg * 8) =
                make_float4(acc[i][0], acc[i][1], acc[i][2], acc[i][3]);
            *(float4*)(Y + (size_t)grow * D + cg * 8 + 4) =
                make_float4(acc[i][4], acc[i][5], acc[i][6], acc[i][7]);
        }
    }
}

// ---------------- BN stats ----------------
__global__ __launch_bounds__(128) void k_bn_stats(const float* __restrict__ A,
                                                  float* __restrict__ sums, int n) {
    int j = threadIdx.x;
    float s = 0.f, ss = 0.f;
    for (int r = blockIdx.x; r < n; r += gridDim.x) {
        float v = A[(size_t)r * D + j];
        s += v;
        ss += v * v;
    }
    atomicAdd(&sums[j], s);
    atomicAdd(&sums[D + j], ss);
}

// sc[0:128]=scale, sc[128:256]=shift.  (b1 cancels exactly in BN — omitted.)
__global__ __launch_bounds__(128) void k_bn_finalize(const float* __restrict__ sums,
                                                     const float* __restrict__ gamma,
                                                     const float* __restrict__ beta,
                                                     float* __restrict__ sc, int n) {
    int j = threadIdx.x;
    float inv_n = 1.0f / (float)n;
    float mu = sums[j] * inv_n;
    float var = sums[D + j] * inv_n - mu * mu;
    float is = rsqrtf(var + BN_EPS);
    float scale = gamma[j] * is;
    sc[j] = scale;
    sc[D + j] = beta[j] - mu * scale;
}

extern "C" void kernel_launch(void* const* d_in, const int* in_sizes, int n_in,
                              void* d_out, int out_size, void* d_ws, size_t ws_size,
                              hipStream_t stream) {
    const float* x     = (const float*)d_in[0];
    const int*   ei    = (const int*)d_in[1];
    const float* W1    = (const float*)d_in[2];
    // d_in[3] = b1 — cancels exactly in BatchNorm, unused
    const float* gamma = (const float*)d_in[4];
    const float* beta  = (const float*)d_in[5];
    const float* W2    = (const float*)d_in[6];
    const float* b2    = (const float*)d_in[7];
    float* out = (float*)d_out;

    int n = in_sizes[0] / D;   // 50000
    int E = in_sizes[1] / 2;   // 800000
    const int* src = ei;
    const int* dst = ei + E;
    int nb = (n + 1023) / 1024;  // scan blocks (49) — must be <= 256

    char* ws = (char*)d_ws;
    size_t off = 0;
    auto alloc = [&](size_t bytes) {
        char* p = ws + off;
        off = (off + bytes + 511) & ~(size_t)511;
        return p;
    };
    size_t szH = (size_t)n * D * sizeof(float);
    float* h       = (float*)alloc(szH);
    float* agg     = (float*)alloc(szH);
    float* dinv    = (float*)alloc(n * sizeof(float));
    int*   cnt     = (int*)alloc(n * sizeof(int));
    int*   rowptr  = (int*)alloc((n + 1) * sizeof(int));
    int*   cursor  = (int*)alloc(n * sizeof(int));
    int*   bsum    = (int*)alloc(256 * sizeof(int));
    int*   csr_src = (int*)alloc((size_t)E * sizeof(int));
    float* csr_w   = (float*)alloc((size_t)E * sizeof(float));
    float* sums    = (float*)alloc(2 * D * sizeof(float));
    float* sc      = (float*)alloc(2 * D * sizeof(float));

    hipMemsetAsync(cnt, 0, n * sizeof(int), stream);
    hipMemsetAsync(sums, 0, 2 * D * sizeof(float), stream);

    // CSR build: count -> 3-phase scan (+dinv fused) -> scatter
    k_count<<<(E + 255) / 256, 256, 0, stream>>>(dst, cnt, E);
    k_scanA<<<nb, 256, 0, stream>>>(cnt, bsum, n);
    k_scanB<<<1, 256, 0, stream>>>(bsum, rowptr, nb, n);
    k_scanC<<<nb, 256, 0, stream>>>(cnt, bsum, rowptr, cursor, dinv, n);
    k_scatter<<<(E + 255) / 256, 256, 0, stream>>>(src, dst, dinv, cursor,
                                                   csr_src, csr_w, E);

    // conv1: h = x @ W1 ; agg = norm-aggregate(h)   (b1 cancels in BN)
    k_gemm<<<(n + 63) / 64, 256, 0, stream>>>(x, W1, nullptr, h, n);
    k_agg_rows<<<(n + 3) / 4, 256, 0, stream>>>(h, rowptr, csr_src, csr_w, dinv,
                                                nullptr, agg, n);

    // BN stats -> scale/shift (ReLU fused into GEMM2 load)
    k_bn_stats<<<512, 128, 0, stream>>>(agg, sums, n);
    k_bn_finalize<<<1, 128, 0, stream>>>(sums, gamma, beta, sc, n);

    // conv2: h = relu(BN(agg)) @ W2 ; out = norm-aggregate(h) + b2
    k_gemm<<<(n + 63) / 64, 256, 0, stream>>>(agg, W2, sc, h, n);
    k_agg_rows<<<(n + 3) / 4, 256, 0, stream>>>(h, rowptr, csr_src, csr_w, dinv,
                                                b2, out, n);
}

// Round 4
// 351.195 us; speedup vs baseline: 9.9212x; 1.1322x over previous
//
#include <hip/hip_runtime.h>

#define D 128
#define BN_EPS 1e-5f

// RNE-pack two f32 into a bf16 pair (lo = element 0, hi = element 1)
__device__ __forceinline__ unsigned bf16pair(float a, float b) {
    unsigned ua = __float_as_uint(a), ub = __float_as_uint(b);
    ua += 0x7fff + ((ua >> 16) & 1);
    ub += 0x7fff + ((ub >> 16) & 1);
    return (ua >> 16) | (ub & 0xffff0000u);
}

// ---------------- degree count ----------------
__global__ __launch_bounds__(256) void k_count(const int* __restrict__ dst,
                                               int* __restrict__ cnt, int E) {
    int e = blockIdx.x * 256 + threadIdx.x;
    if (e < E) atomicAdd(&cnt[dst[e]], 1);
}

// ---------------- 3-phase exclusive scan over cnt[0:n] ----------------
__global__ __launch_bounds__(256) void k_scanA(const int* __restrict__ cnt,
                                               int* __restrict__ bsum, int n) {
    int tid = threadIdx.x;
    int base = blockIdx.x * 1024 + tid * 4;
    int s = 0;
#pragma unroll
    for (int i = 0; i < 4; i++) {
        int idx = base + i;
        if (idx < n) s += cnt[idx];
    }
#pragma unroll
    for (int off = 32; off; off >>= 1) s += __shfl_down(s, off, 64);
    __shared__ int ws[4];
    if ((tid & 63) == 0) ws[tid >> 6] = s;
    __syncthreads();
    if (tid == 0) bsum[blockIdx.x] = ws[0] + ws[1] + ws[2] + ws[3];
}

__global__ __launch_bounds__(256) void k_scanB(int* __restrict__ bsum,
                                               int* __restrict__ rowptr,
                                               int nb, int n) {
    __shared__ int sh[256];
    int tid = threadIdx.x;
    int v = (tid < nb) ? bsum[tid] : 0;
    sh[tid] = v;
    __syncthreads();
    for (int off = 1; off < 256; off <<= 1) {
        int u = (tid >= off) ? sh[tid - off] : 0;
        __syncthreads();
        sh[tid] += u;
        __syncthreads();
    }
    if (tid < nb) bsum[tid] = sh[tid] - v;   // exclusive
    if (tid == nb - 1) rowptr[n] = sh[tid];  // total
}

__global__ __launch_bounds__(256) void k_scanC(const int* __restrict__ cnt,
                                               const int* __restrict__ bsum,
                                               int* __restrict__ rowptr,
                                               int* __restrict__ cursor,
                                               float* __restrict__ dinv, int n) {
    int tid = threadIdx.x;
    int base = blockIdx.x * 1024 + tid * 4;
    int c[4];
    int s = 0;
#pragma unroll
    for (int i = 0; i < 4; i++) {
        int idx = base + i;
        c[i] = (idx < n) ? cnt[idx] : 0;
        s += c[i];
    }
    int inc = s;
#pragma unroll
    for (int off = 1; off < 64; off <<= 1) {
        int u = __shfl_up(inc, off, 64);
        if ((tid & 63) >= off) inc += u;
    }
    __shared__ int wtot[4];
    if ((tid & 63) == 63) wtot[tid >> 6] = inc;
    __syncthreads();
    int woff = 0, w = tid >> 6;
    for (int i = 0; i < w; i++) woff += wtot[i];
    int ex = inc - s + woff + bsum[blockIdx.x];
#pragma unroll
    for (int i = 0; i < 4; i++) {
        int idx = base + i;
        if (idx < n) {
            rowptr[idx] = ex;
            cursor[idx] = ex;
            dinv[idx] = rsqrtf((float)(c[i] + 1));  // +1 = self loop
            ex += c[i];
        }
    }
}

// ---------------- scatter edges into packed CSR {src, dinv[src]} ----------------
__global__ __launch_bounds__(256) void k_scatter(const int* __restrict__ src,
                                                 const int* __restrict__ dst,
                                                 const float* __restrict__ dinv,
                                                 int* __restrict__ cursor,
                                                 int2* __restrict__ csr, int E) {
    int e = blockIdx.x * 256 + threadIdx.x;
    if (e >= E) return;
    int s = src[e], t = dst[e];
    int pos = atomicAdd(&cursor[t], 1);
    csr[pos] = make_int2(s, __float_as_int(dinv[s]));
}

// ---------------- gather aggregation: one wave per output row ----------------
// OUT pre-initialized by GEMM epilogue with dinv[t]*h[t] (f32 self term).
// OUT[t] = ( init[t] + sum_{s in N(t)} dinv[s]*Hb[s] ) * dinv[t] + bias
__global__ __launch_bounds__(256) void k_agg_rows(const unsigned* __restrict__ Hb,
                                                  const int2* __restrict__ csr,
                                                  const int* __restrict__ rowptr,
                                                  const float* __restrict__ dinv,
                                                  const float* __restrict__ bias,
                                                  float* __restrict__ OUT, int n) {
    int row = blockIdx.x * 4 + (threadIdx.x >> 6);
    if (row >= n) return;
    int lane = threadIdx.x & 63;
    float2 acc = ((const float2*)OUT)[(size_t)row * 64 + lane];  // f32 self term
    int k0 = rowptr[row], k1 = rowptr[row + 1];
    int k = k0;
    for (; k + 4 <= k1; k += 4) {
        int2 e0 = csr[k], e1 = csr[k + 1], e2 = csr[k + 2], e3 = csr[k + 3];
        unsigned u0 = Hb[(size_t)e0.x * 64 + lane];
        unsigned u1 = Hb[(size_t)e1.x * 64 + lane];
        unsigned u2 = Hb[(size_t)e2.x * 64 + lane];
        unsigned u3 = Hb[(size_t)e3.x * 64 + lane];
        float w0 = __int_as_float(e0.y), w1 = __int_as_float(e1.y);
        float w2 = __int_as_float(e2.y), w3 = __int_as_float(e3.y);
        acc.x = fmaf(w0, __uint_as_float(u0 << 16), acc.x);
        acc.y = fmaf(w0, __uint_as_float(u0 & 0xffff0000u), acc.y);
        acc.x = fmaf(w1, __uint_as_float(u1 << 16), acc.x);
        acc.y = fmaf(w1, __uint_as_float(u1 & 0xffff0000u), acc.y);
        acc.x = fmaf(w2, __uint_as_float(u2 << 16), acc.x);
        acc.y = fmaf(w2, __uint_as_float(u2 & 0xffff0000u), acc.y);
        acc.x = fmaf(w3, __uint_as_float(u3 << 16), acc.x);
        acc.y = fmaf(w3, __uint_as_float(u3 & 0xffff0000u), acc.y);
    }
    for (; k < k1; k++) {
        int2 e = csr[k];
        unsigned u = Hb[(size_t)e.x * 64 + lane];
        float w = __int_as_float(e.y);
        acc.x = fmaf(w, __uint_as_float(u << 16), acc.x);
        acc.y = fmaf(w, __uint_as_float(u & 0xffff0000u), acc.y);
    }
    float dt = dinv[row];
    acc.x *= dt;
    acc.y *= dt;
    if (bias) {
        float2 b = ((const float2*)bias)[lane];
        acc.x += b.x;
        acc.y += b.y;
    }
    ((float2*)OUT)[(size_t)row * 64 + lane] = acc;
}

// ---------------- tiled GEMM: h = f(X) @ W ----------------
// Epilogue writes: Yinit[r,:] = dinv[r]*h[r,:]  (f32, self-loop term)
//                  Yb[r,:]    = bf16(h[r,:])    (gather payload)
// f = identity if sc==null, else relu(x*scale + shift), sc[0:128]=scale, sc[128:256]=shift
#define XS_STRIDE 68
__global__ __launch_bounds__(256) void k_gemm(const float* __restrict__ X,
                                              const float* __restrict__ W,
                                              const float* __restrict__ sc,
                                              const float* __restrict__ dinv,
                                              float* __restrict__ Yinit,
                                              unsigned* __restrict__ Yb, int n) {
    __shared__ float XsT[32 * XS_STRIDE];   // [kk][row], transposed chunk
    __shared__ float Ws[32 * 132];          // [kk][c], padded stride
    int tid = threadIdx.x;
    int row0 = blockIdx.x * 64;
    int rg = tid & 15;   // rows rg*4 .. rg*4+3
    int cg = tid >> 4;   // cols cg*8 .. cg*8+7
    float acc[4][8];
#pragma unroll
    for (int i = 0; i < 4; i++)
#pragma unroll
        for (int j = 0; j < 8; j++) acc[i][j] = 0.f;

    for (int kc = 0; kc < 4; kc++) {
        __syncthreads();
        {
            int idx = tid;
#pragma unroll
            for (int p = 0; p < 4; p++, idx += 256) {
                int k = idx >> 5, c4 = idx & 31;
                float4 w = ((const float4*)(W + (size_t)(kc * 32 + k) * D))[c4];
                float* dpt = &Ws[k * 132 + c4 * 4];
                dpt[0] = w.x; dpt[1] = w.y; dpt[2] = w.z; dpt[3] = w.w;
            }
        }
        {
            int r = tid >> 3, kq = tid & 7;
#pragma unroll
            for (int p = 0; p < 2; p++, r += 32) {
                int grow = row0 + r;
                float4 v = make_float4(0.f, 0.f, 0.f, 0.f);
                if (grow < n)
                    v = *(const float4*)(X + (size_t)grow * D + kc * 32 + kq * 4);
                if (sc) {
                    int c4 = kc * 8 + kq;
                    float4 scl = ((const float4*)sc)[c4];
                    float4 sh  = ((const float4*)(sc + D))[c4];
                    v.x = fmaxf(fmaf(v.x, scl.x, sh.x), 0.f);
                    v.y = fmaxf(fmaf(v.y, scl.y, sh.y), 0.f);
                    v.z = fmaxf(fmaf(v.z, scl.z, sh.z), 0.f);
                    v.w = fmaxf(fmaf(v.w, scl.w, sh.w), 0.f);
                }
                XsT[(kq * 4 + 0) * XS_STRIDE + r] = v.x;
                XsT[(kq * 4 + 1) * XS_STRIDE + r] = v.y;
                XsT[(kq * 4 + 2) * XS_STRIDE + r] = v.z;
                XsT[(kq * 4 + 3) * XS_STRIDE + r] = v.w;
            }
        }
        __syncthreads();
#pragma unroll 4
        for (int kk = 0; kk < 32; kk++) {
            float4 xv = *(const float4*)&XsT[kk * XS_STRIDE + rg * 4];
            float4 wa = *(const float4*)&Ws[kk * 132 + cg * 8];
            float4 wb = *(const float4*)&Ws[kk * 132 + cg * 8 + 4];
            float xr[4] = {xv.x, xv.y, xv.z, xv.w};
            float wc[8] = {wa.x, wa.y, wa.z, wa.w, wb.x, wb.y, wb.z, wb.w};
#pragma unroll
            for (int i = 0; i < 4; i++)
#pragma unroll
                for (int j = 0; j < 8; j++)
                    acc[i][j] = fmaf(xr[i], wc[j], acc[i][j]);
        }
    }
#pragma unroll
    for (int i = 0; i < 4; i++) {
        int grow = row0 + rg * 4 + i;
        if (grow < n) {
            float dt = dinv[grow];
            *(float4*)(Yinit + (size_t)grow * D + cg * 8) =
                make_float4(dt * acc[i][0], dt * acc[i][1], dt * acc[i][2], dt * acc[i][3]);
            *(float4*)(Yinit + (size_t)grow * D + cg * 8 + 4) =
                make_float4(dt * acc[i][4], dt * acc[i][5], dt * acc[i][6], dt * acc[i][7]);
            uint4 pk;
            pk.x = bf16pair(acc[i][0], acc[i][1]);
            pk.y = bf16pair(acc[i][2], acc[i][3]);
            pk.z = bf16pair(acc[i][4], acc[i][5]);
            pk.w = bf16pair(acc[i][6], acc[i][7]);
            ((uint4*)Yb)[(size_t)grow * 16 + cg] = pk;
        }
    }
}

// ---------------- BN stats ----------------
__global__ __launch_bounds__(128) void k_bn_stats(const float* __restrict__ A,
                                                  float* __restrict__ sums, int n) {
    int j = threadIdx.x;
    float s = 0.f, ss = 0.f;
    for (int r = blockIdx.x; r < n; r += gridDim.x) {
        float v = A[(size_t)r * D + j];
        s += v;
        ss += v * v;
    }
    atomicAdd(&sums[j], s);
    atomicAdd(&sums[D + j], ss);
}

// sc[0:128]=scale, sc[128:256]=shift.  (b1 cancels exactly in BN — omitted.)
__global__ __launch_bounds__(128) void k_bn_finalize(const float* __restrict__ sums,
                                                     const float* __restrict__ gamma,
                                                     const float* __restrict__ beta,
                                                     float* __restrict__ sc, int n) {
    int j = threadIdx.x;
    float inv_n = 1.0f / (float)n;
    float mu = sums[j] * inv_n;
    float var = sums[D + j] * inv_n - mu * mu;
    float is = rsqrtf(var + BN_EPS);
    float scale = gamma[j] * is;
    sc[j] = scale;
    sc[D + j] = beta[j] - mu * scale;
}

extern "C" void kernel_launch(void* const* d_in, const int* in_sizes, int n_in,
                              void* d_out, int out_size, void* d_ws, size_t ws_size,
                              hipStream_t stream) {
    const float* x     = (const float*)d_in[0];
    const int*   ei    = (const int*)d_in[1];
    const float* W1    = (const float*)d_in[2];
    // d_in[3] = b1 — cancels exactly in BatchNorm, unused
    const float* gamma = (const float*)d_in[4];
    const float* beta  = (const float*)d_in[5];
    const float* W2    = (const float*)d_in[6];
    const float* b2    = (const float*)d_in[7];
    float* out = (float*)d_out;

    int n = in_sizes[0] / D;   // 50000
    int E = in_sizes[1] / 2;   // 800000
    const int* src = ei;
    const int* dst = ei + E;
    int nb = (n + 1023) / 1024;  // scan blocks (49) — must be <= 256

    char* ws = (char*)d_ws;
    size_t off = 0;
    auto alloc = [&](size_t bytes) {
        char* p = ws + off;
        off = (off + bytes + 511) & ~(size_t)511;
        return p;
    };
    size_t szH = (size_t)n * D * sizeof(float);
    float*    agg    = (float*)alloc(szH);                       // conv1 dest / BN input
    unsigned* hbf    = (unsigned*)alloc((size_t)n * D * 2);      // bf16 gather payload
    float*    dinv   = (float*)alloc(n * sizeof(float));
    int*      cnt    = (int*)alloc(n * sizeof(int));
    int*      rowptr = (int*)alloc((n + 1) * sizeof(int));
    int*      cursor = (int*)alloc(n * sizeof(int));
    int*      bsum   = (int*)alloc(256 * sizeof(int));
    int2*     csr    = (int2*)alloc((size_t)E * sizeof(int2));
    float*    sums   = (float*)alloc(2 * D * sizeof(float));
    float*    sc     = (float*)alloc(2 * D * sizeof(float));

    hipMemsetAsync(cnt, 0, n * sizeof(int), stream);
    hipMemsetAsync(sums, 0, 2 * D * sizeof(float), stream);

    // CSR build: count -> 3-phase scan (+dinv fused) -> packed scatter
    k_count<<<(E + 255) / 256, 256, 0, stream>>>(dst, cnt, E);
    k_scanA<<<nb, 256, 0, stream>>>(cnt, bsum, n);
    k_scanB<<<1, 256, 0, stream>>>(bsum, rowptr, nb, n);
    k_scanC<<<nb, 256, 0, stream>>>(cnt, bsum, rowptr, cursor, dinv, n);
    k_scatter<<<(E + 255) / 256, 256, 0, stream>>>(src, dst, dinv, cursor, csr, E);

    // conv1: h = x@W1 (f32 self-term into agg, bf16 into hbf); aggregate
    k_gemm<<<(n + 63) / 64, 256, 0, stream>>>(x, W1, nullptr, dinv, agg, hbf, n);
    k_agg_rows<<<(n + 3) / 4, 256, 0, stream>>>(hbf, csr, rowptr, dinv, nullptr, agg, n);

    // BN stats -> scale/shift (ReLU fused into GEMM2 load)
    k_bn_stats<<<512, 128, 0, stream>>>(agg, sums, n);
    k_bn_finalize<<<1, 128, 0, stream>>>(sums, gamma, beta, sc, n);

    // conv2: h = relu(BN(agg))@W2 (self-term into out, bf16 into hbf); aggregate + b2
    k_gemm<<<(n + 63) / 64, 256, 0, stream>>>(agg, W2, sc, dinv, out, hbf, n);
    k_agg_rows<<<(n + 3) / 4, 256, 0, stream>>>(hbf, csr, rowptr, dinv, b2, out, n);
}